// Round 17
// baseline (300.910 us; speedup 1.0000x reference)
//
#include <hip/hip_runtime.h>
#include <hip/hip_bf16.h>
#include <stdint.h>

#define N_TOK 16384
#define D_IN  2048
#define D_HID 2048

typedef __attribute__((ext_vector_type(8))) short  bf16x8;
typedef __attribute__((ext_vector_type(4))) float  f32x4;
typedef __attribute__((ext_vector_type(8))) unsigned short u16x8;

__device__ __forceinline__ unsigned short f2bf(float f) {
    unsigned int u = __float_as_uint(f);
    u = (u + 0x7FFFu + ((u >> 16) & 1u)) >> 16;
    return (unsigned short)u;
}

// ------------------------------------------ gate0: token-0 expert indices --
// Top-2 on logits+bias; argmax order is invariant under softmax (monotone),
// so indices match the reference's softmax-then-top-k.
__global__ void gate0_kernel(const float* __restrict__ x,
                             const float* __restrict__ Wg,
                             const float* __restrict__ bg,
                             int* __restrict__ eidx) {
    const int lane = threadIdx.x;
    float acc[8];
#pragma unroll
    for (int e = 0; e < 8; ++e) acc[e] = 0.f;
    for (int i = lane; i < D_IN; i += 64) {
        float xv = x[i];
        const float4* wr = (const float4*)(Wg + (size_t)i * 8);
        float4 w0 = wr[0], w1 = wr[1];
        acc[0] += xv * w0.x; acc[1] += xv * w0.y;
        acc[2] += xv * w0.z; acc[3] += xv * w0.w;
        acc[4] += xv * w1.x; acc[5] += xv * w1.y;
        acc[6] += xv * w1.z; acc[7] += xv * w1.w;
    }
#pragma unroll
    for (int off = 32; off > 0; off >>= 1)
#pragma unroll
        for (int e = 0; e < 8; ++e) acc[e] += __shfl_xor(acc[e], off);
    if (lane == 0) {
        float s1 = -1e30f, s2 = -1e30f; int i1 = 0, i2 = 0;
#pragma unroll
        for (int e = 0; e < 8; ++e) {
            float g = acc[e] + bg[e];
            if (g > s1)      { s2 = s1; i2 = i1; s1 = g; i1 = e; }
            else if (g > s2) { s2 = g;  i2 = e; }
        }
        eidx[0] = i1; eidx[1] = i2;
    }
}

// -------- fused prep: xconv3 slabs + gate partials | wconv (role-split) ---
// blocks 0..511: xconv3 (R16-proven): 8 kt/block, gate partial in regs,
//   one 32-B partial store per thread.
// blocks 512..2559: wconv (R16-proven body): W[e0],W[e1] -> bf16 slabs;
//   eidx available from gate0. Rides inside xconv3's BW-bound window.
__global__ __launch_bounds__(256) void prep_kernel(
    const float* __restrict__ x, const float* __restrict__ Wg,
    const float* __restrict__ W, const int* __restrict__ eidx,
    unsigned short* __restrict__ xb, float* __restrict__ part,
    unsigned short* __restrict__ wbT) {
    __shared__ float tile[64][65];
    const int bid = blockIdx.x;
    const int t   = threadIdx.x;
    if (bid < 512) {
        const int mt = bid >> 3;
        const int g  = bid & 7;
        float p[8];
#pragma unroll
        for (int e = 0; e < 8; ++e) p[e] = 0.f;
#pragma unroll
        for (int q = 0; q < 8; ++q) {
            const int kt = g * 8 + q;
            const float* src = x + ((size_t)(mt * 256 + t)) * D_IN + kt * 32;
            unsigned short* slab = xb + ((size_t)(mt * 64 + kt)) * 8192;
            const float* wg = Wg + kt * 32 * 8;   // wave-uniform -> s_load
#pragma unroll
            for (int ks = 0; ks < 4; ++ks) {
                float4 a = *(const float4*)(src + ks * 8);
                float4 b = *(const float4*)(src + ks * 8 + 4);
                float xv[8] = {a.x, a.y, a.z, a.w, b.x, b.y, b.z, b.w};
                u16x8 v;
#pragma unroll
                for (int j = 0; j < 8; ++j) v[j] = f2bf(xv[j]);
                *(u16x8*)(slab + (ks * 256 + t) * 8) = v;
#pragma unroll
                for (int j = 0; j < 8; ++j)
#pragma unroll
                    for (int e = 0; e < 8; ++e)
                        p[e] += xv[j] * wg[(ks * 8 + j) * 8 + e];
            }
        }
        float* dst = part + (((size_t)(mt * 8 + g)) * 256 + t) * 8;
#pragma unroll
        for (int e = 0; e < 8; ++e) dst[e] = p[e];
        return;
    }
    // ---- wconv role ----
    const int bid2 = bid - 512;
    const int nx   = bid2 & 31;
    const int ky   = (bid2 >> 5) & 31;
    const int be   = bid2 >> 10;
    const int e    = eidx[be];
    const int k0   = ky * 64;
    const int n0   = nx * 64;
    const int bx   = n0 >> 7;
    const int cl0  = n0 & 127;
    const int kt0  = k0 >> 5;
    const float* src = W + (size_t)e * D_IN * D_HID;

#pragma unroll
    for (int p = 0; p < 4; ++p) {
        int row = p * 16 + (t >> 4);
        int col = (t & 15) * 4;
        const float* s = src + (size_t)(k0 + row) * D_HID + n0 + col;
        tile[row][col]     = s[0];
        tile[row][col + 1] = s[1];
        tile[row][col + 2] = s[2];
        tile[row][col + 3] = s[3];
    }
    __syncthreads();

    const int g   = (t >> 5) * 8;
    const int ktl = t >> 7;
    const int ks  = (t >> 5) & 3;
#pragma unroll
    for (int p = 0; p < 2; ++p) {
        int n = p * 32 + (t & 31);
        u16x8 v;
#pragma unroll
        for (int j = 0; j < 8; ++j) v[j] = f2bf(tile[g + j][n]);
        unsigned short* dst = wbT + ((size_t)(bx * 64 + kt0 + ktl)) * 8192 +
                              ((size_t)(ks * 256 + be * 128 + cl0 + n)) * 8;
        *(u16x8*)dst = v;
    }
}

// ---------------- gatefin: reduce 8 partials -> softmax -> top-2 ----------
__global__ __launch_bounds__(256) void gatefin_kernel(
    const float* __restrict__ part, const float* __restrict__ bg,
    float* __restrict__ s12) {
    __shared__ float red[4][64][8];
    const int mt  = blockIdx.x >> 2;
    const int q   = blockIdx.x & 3;
    const int tok = threadIdx.x & 63;
    const int s   = threadIdx.x >> 6;

    float l8[8];
#pragma unroll
    for (int e = 0; e < 8; ++e) l8[e] = 0.f;
#pragma unroll
    for (int gg = 0; gg < 2; ++gg) {
        const int gidx = s * 2 + gg;
        const float* pp =
            part + (((size_t)(mt * 8 + gidx)) * 256 + q * 64 + tok) * 8;
        float4 a = *(const float4*)pp;
        float4 b = *(const float4*)(pp + 4);
        l8[0] += a.x; l8[1] += a.y; l8[2] += a.z; l8[3] += a.w;
        l8[4] += b.x; l8[5] += b.y; l8[6] += b.z; l8[7] += b.w;
    }
#pragma unroll
    for (int e = 0; e < 8; ++e) red[s][tok][e] = l8[e];
    __syncthreads();
    if (s == 0) {
        float mx = -1e30f;
#pragma unroll
        for (int e = 0; e < 8; ++e) {
            l8[e] = red[0][tok][e] + red[1][tok][e] + red[2][tok][e] +
                    red[3][tok][e] + bg[e];
            mx = fmaxf(mx, l8[e]);
        }
        float sum = 0.f;
#pragma unroll
        for (int e = 0; e < 8; ++e) { l8[e] = expf(l8[e] - mx); sum += l8[e]; }
        float inv = 1.f / sum;
        float s1 = -1.f, s2 = -1.f;
#pragma unroll
        for (int e = 0; e < 8; ++e) {
            float g = l8[e] * inv;
            if (g > s1)      { s2 = s1; s1 = g; }
            else if (g > s2) { s2 = g; }
        }
        const int token = mt * 256 + q * 64 + tok;
        s12[token * 2]     = s1;
        s12[token * 2 + 1] = s2;
    }
}

// ------------------------------------------------------------------ GEMM --
// R14-R16 best state (byte-identical): one barrier per K-tile {12 ds_read |
// 4 gload_lds | vmcnt(4) | bar | 32 MFMA}, 4 buffers depth-3 slab staging,
// 16x16x32 MFMA, setprio, XCD swizzle (B L2-resident).
#define GLD16(gp, lp)                                                        \
    __builtin_amdgcn_global_load_lds(                                        \
        (const __attribute__((address_space(1))) void*)(gp),                 \
        (__attribute__((address_space(3))) void*)(lp), 16, 0, 0)

#define LDSV(SLOT) (*(const bf16x8*)&lds[(SLOT) * 8])

#define STAGE_A(SBAS, KT)                                                    \
    do {                                                                     \
        GLD16(gA0 + (size_t)(KT) * 8192,        &lds[((SBAS) + t512) * 8]);  \
        GLD16(gA0 + (size_t)(KT) * 8192 + 4096, &lds[((SBAS) + 512 + t512) * 8]); \
    } while (0)
#define STAGE_B(SBAS, KT)                                                    \
    do {                                                                     \
        GLD16(gB0 + (size_t)(KT) * 8192,        &lds[((SBAS) + 1024 + t512) * 8]); \
        GLD16(gB0 + (size_t)(KT) * 8192 + 4096, &lds[((SBAS) + 1536 + t512) * 8]); \
    } while (0)

#define MF(MI, AV)                                                                              \
    acc[MI][0] = __builtin_amdgcn_mfma_f32_16x16x32_bf16(AV, bf0, acc[MI][0], 0, 0, 0);         \
    acc[MI][1] = __builtin_amdgcn_mfma_f32_16x16x32_bf16(AV, bf1, acc[MI][1], 0, 0, 0);         \
    acc[MI][2] = __builtin_amdgcn_mfma_f32_16x16x32_bf16(AV, bf2, acc[MI][2], 0, 0, 0);         \
    acc[MI][3] = __builtin_amdgcn_mfma_f32_16x16x32_bf16(AV, bf3, acc[MI][3], 0, 0, 0);

#define TILE(RB, SB, KT, DO_STAGE, VMSTR)                                    \
    do {                                                                     \
        const int rbas  = (RB) * 2048;                                       \
        const int abase = rbas + aks + arow;                                 \
        const int bbase = rbas + 1024 + aks + brow;                          \
        bf16x8 bf0 = LDSV(bbase), bf1 = LDSV(bbase + 16),                    \
               bf2 = LDSV(bbase + 32), bf3 = LDSV(bbase + 48);               \
        bf16x8 a0 = LDSV(abase), a1 = LDSV(abase + 16),                      \
               a2 = LDSV(abase + 32), a3 = LDSV(abase + 48);                 \
        bf16x8 a4 = LDSV(abase + 64), a5 = LDSV(abase + 80),                 \
               a6 = LDSV(abase + 96), a7 = LDSV(abase + 112);                \
        if (DO_STAGE) { STAGE_A((SB) * 2048, KT); STAGE_B((SB) * 2048, KT); }\
        if (VMSTR[0]) asm volatile(VMSTR ::: "memory");                      \
        __builtin_amdgcn_s_barrier();                                        \
        __builtin_amdgcn_s_setprio(1);                                       \
        MF(0, a0) MF(1, a1) MF(2, a2) MF(3, a3)                              \
        MF(4, a4) MF(5, a5) MF(6, a6) MF(7, a7)                              \
        __builtin_amdgcn_s_setprio(0);                                       \
    } while (0)

__global__ __launch_bounds__(512, 2) void moe_gemm_kernel(
    const unsigned short* __restrict__ xb,   // slab order [mt64][kt64][1024]
    const unsigned short* __restrict__ wbT,  // slab order [bx16][kt64][1024]
    const float* __restrict__ b_exp,         // [8][D_HID]
    const int* __restrict__ eidx,
    const float* __restrict__ s12,           // [N_TOK][2]
    float* __restrict__ out) {
    __shared__ __align__(16) short lds[4 * 2048 * 8];  // 128 KiB

    const int t512 = threadIdx.x;
    const int lane = t512 & 63;
    const int w    = t512 >> 6;
    const int wm   = w >> 2;
    const int wn   = w & 3;

    const int bid = blockIdx.x;
    const int xcd = bid & 7;
    const int jb  = bid >> 3;
    const int bx  = xcd * 2 + (jb & 1);
    const int by  = jb >> 1;
    const int mbase = by * 256;
    const int nbase = bx * 128;

    const unsigned short* gA0 = xb  + ((size_t)by * 64) * 8192 + t512 * 8;
    const unsigned short* gB0 = wbT + ((size_t)bx * 64) * 8192 + t512 * 8;

    const int aks  = (lane >> 4) * 256;
    const int arow = wm * 128 + (lane & 15);
    const int brow = wn * 64 + (lane & 15);

    f32x4 acc[8][4];
#pragma unroll
    for (int mi = 0; mi < 8; ++mi)
#pragma unroll
        for (int ni = 0; ni < 4; ++ni) acc[mi][ni] = (f32x4){0.f, 0.f, 0.f, 0.f};

    STAGE_A(0, 0);    STAGE_B(0, 0);
    STAGE_A(2048, 1); STAGE_B(2048, 1);
    STAGE_A(4096, 2); STAGE_B(4096, 2);
    asm volatile("s_waitcnt vmcnt(4)" ::: "memory");
    __builtin_amdgcn_s_barrier();

#pragma unroll 4
    for (int t = 0; t < 61; ++t) {
        TILE(t & 3, (t + 3) & 3, t + 3, 1, "s_waitcnt vmcnt(4)");
    }
    TILE(1, 0, 0, 0, "s_waitcnt vmcnt(4)");   // tile 61 (no wait in practice)
    TILE(2, 0, 0, 0, "s_waitcnt vmcnt(0)");   // tile 62: retire tile 63
    TILE(3, 0, 0, 0, "");                     // tile 63

    // -------- epilogue: combine experts through LDS (f32) --------
    __syncthreads();
    float* fl = (float*)lds;
    if (wn >= 2) {
        float* reg = fl + (wm * 2 + (wn - 2)) * 8192;   // [128][64]
#pragma unroll
        for (int mi = 0; mi < 8; ++mi)
#pragma unroll
            for (int ni = 0; ni < 4; ++ni)
#pragma unroll
                for (int j = 0; j < 4; ++j) {
                    int row_l = mi * 16 + ((lane >> 4) << 2) + j;
                    int col_l = ni * 16 + (lane & 15);
                    reg[row_l * 64 + col_l] = acc[mi][ni][j];
                }
    }
    __syncthreads();
    if (wn < 2) {
        const float* reg = fl + (wm * 2 + wn) * 8192;
        const int e0 = eidx[0], e1 = eidx[1];
        const float* bb0 = b_exp + (size_t)e0 * D_HID;
        const float* bb1 = b_exp + (size_t)e1 * D_HID;
        const float2* s12v = (const float2*)s12;
        int   cc[4];
        float b0c[4], b1c[4];
#pragma unroll
        for (int ni = 0; ni < 4; ++ni) {
            cc[ni]  = nbase + wn * 64 + ni * 16 + (lane & 15);
            b0c[ni] = bb0[cc[ni]];
            b1c[ni] = bb1[cc[ni]];
        }
#pragma unroll
        for (int mi = 0; mi < 8; ++mi)
#pragma unroll
            for (int j = 0; j < 4; ++j) {
                int row_l = mi * 16 + ((lane >> 4) << 2) + j;
                int r = mbase + wm * 128 + row_l;
                float2 s = s12v[r];
#pragma unroll
                for (int ni = 0; ni < 4; ++ni) {
                    float y1 = reg[row_l * 64 + ni * 16 + (lane & 15)];
                    out[(size_t)r * D_HID + cc[ni]] =
                        s.x * (acc[mi][ni][j] + b0c[ni]) + s.y * (y1 + b1c[ni]);
                }
            }
    }
}

// ---------------------------------------------------------------- launch --
extern "C" void kernel_launch(void* const* d_in, const int* in_sizes, int n_in,
                              void* d_out, int out_size, void* d_ws, size_t ws_size,
                              hipStream_t stream) {
    const float* x         = (const float*)d_in[0];
    const float* W_experts = (const float*)d_in[1];
    const float* b_experts = (const float*)d_in[2];
    const float* W_gate    = (const float*)d_in[3];
    const float* b_gate    = (const float*)d_in[4];
    float* out = (float*)d_out;

    char* ws = (char*)d_ws;
    float* s12  = (float*)ws;                                        // 128 KiB
    int*   eidx = (int*)(ws + 131072);
    unsigned short* xb  = (unsigned short*)(ws + 262144);            // 64 MiB
    unsigned short* wbT = (unsigned short*)(ws + 262144 + 67108864); // 16 MiB
    float* part = out;   // 4.2 MB gate partials in d_out scratch (GEMM
                         // fully overwrites out afterwards, every call)

    gate0_kernel<<<1, 64, 0, stream>>>(x, W_gate, b_gate, eidx);
    prep_kernel<<<2560, 256, 0, stream>>>(x, W_gate, W_experts, eidx,
                                          xb, part, wbT);
    gatefin_kernel<<<256, 256, 0, stream>>>(part, b_gate, s12);
    moe_gemm_kernel<<<1024, 512, 0, stream>>>(xb, wbT, b_experts, eidx, s12, out);
}

// Round 18
// 292.019 us; speedup vs baseline: 1.0304x; 1.0304x over previous
//
#include <hip/hip_runtime.h>
#include <hip/hip_bf16.h>
#include <stdint.h>

#define N_TOK 16384
#define D_IN  2048
#define D_HID 2048

typedef __attribute__((ext_vector_type(8))) short  bf16x8;
typedef __attribute__((ext_vector_type(4))) float  f32x4;
typedef __attribute__((ext_vector_type(8))) unsigned short u16x8;

__device__ __forceinline__ unsigned short f2bf(float f) {
    unsigned int u = __float_as_uint(f);
    u = (u + 0x7FFFu + ((u >> 16) & 1u)) >> 16;
    return (unsigned short)u;
}

// ---------------- xconv3: x -> bf16 slabs + gate partials (8 kt/block) ----
__global__ __launch_bounds__(256) void xconv3_kernel(
    const float* __restrict__ x, const float* __restrict__ Wg,
    unsigned short* __restrict__ xb, float* __restrict__ part) {
    const int mt = blockIdx.x >> 3;       // 64 token-tiles
    const int g  = blockIdx.x & 7;        // 8 kt-groups of 8
    const int t  = threadIdx.x;

    float p[8];
#pragma unroll
    for (int e = 0; e < 8; ++e) p[e] = 0.f;

#pragma unroll
    for (int q = 0; q < 8; ++q) {
        const int kt = g * 8 + q;
        const float* src = x + ((size_t)(mt * 256 + t)) * D_IN + kt * 32;
        unsigned short* slab = xb + ((size_t)(mt * 64 + kt)) * 8192;
        const float* wg = Wg + kt * 32 * 8;   // wave-uniform -> s_load path
#pragma unroll
        for (int ks = 0; ks < 4; ++ks) {
            float4 a = *(const float4*)(src + ks * 8);
            float4 b = *(const float4*)(src + ks * 8 + 4);
            float xv[8] = {a.x, a.y, a.z, a.w, b.x, b.y, b.z, b.w};
            u16x8 v;
#pragma unroll
            for (int j = 0; j < 8; ++j) v[j] = f2bf(xv[j]);
            *(u16x8*)(slab + (ks * 256 + t) * 8) = v;
#pragma unroll
            for (int j = 0; j < 8; ++j)
#pragma unroll
                for (int e = 0; e < 8; ++e)
                    p[e] += xv[j] * wg[(ks * 8 + j) * 8 + e];
        }
    }
    float* dst = part + (((size_t)(mt * 8 + g)) * 256 + t) * 8;
#pragma unroll
    for (int e = 0; e < 8; ++e) dst[e] = p[e];
}

// ---------------- gatefin: reduce 8 partials -> softmax -> top-2 ----------
__global__ __launch_bounds__(256) void gatefin_kernel(
    const float* __restrict__ part, const float* __restrict__ bg,
    float* __restrict__ s12, int* __restrict__ eidx) {
    __shared__ float red[4][64][8];
    const int mt  = blockIdx.x >> 2;
    const int q   = blockIdx.x & 3;
    const int tok = threadIdx.x & 63;
    const int s   = threadIdx.x >> 6;

    float l8[8];
#pragma unroll
    for (int e = 0; e < 8; ++e) l8[e] = 0.f;
#pragma unroll
    for (int gg = 0; gg < 2; ++gg) {
        const int gidx = s * 2 + gg;
        const float* pp =
            part + (((size_t)(mt * 8 + gidx)) * 256 + q * 64 + tok) * 8;
        float4 a = *(const float4*)pp;
        float4 b = *(const float4*)(pp + 4);
        l8[0] += a.x; l8[1] += a.y; l8[2] += a.z; l8[3] += a.w;
        l8[4] += b.x; l8[5] += b.y; l8[6] += b.z; l8[7] += b.w;
    }
#pragma unroll
    for (int e = 0; e < 8; ++e) red[s][tok][e] = l8[e];
    __syncthreads();
    if (s == 0) {
        float mx = -1e30f;
#pragma unroll
        for (int e = 0; e < 8; ++e) {
            l8[e] = red[0][tok][e] + red[1][tok][e] + red[2][tok][e] +
                    red[3][tok][e] + bg[e];
            mx = fmaxf(mx, l8[e]);
        }
        float sum = 0.f;
#pragma unroll
        for (int e = 0; e < 8; ++e) { l8[e] = expf(l8[e] - mx); sum += l8[e]; }
        float inv = 1.f / sum;
        float s1 = -1.f, s2 = -1.f; int i1 = 0, i2 = 0;
#pragma unroll
        for (int e = 0; e < 8; ++e) {
            float g = l8[e] * inv;
            if (g > s1)      { s2 = s1; i2 = i1; s1 = g; i1 = e; }
            else if (g > s2) { s2 = g;  i2 = e; }
        }
        const int token = mt * 256 + q * 64 + tok;
        s12[token * 2]     = s1;
        s12[token * 2 + 1] = s2;
        if (token == 0) { eidx[0] = i1; eidx[1] = i2; }
    }
}

// --------------------- W[e0],W[e1] -> bf16 slab order (transposed) --------
__global__ void wconv_kernel(const float* __restrict__ W,
                             const int* __restrict__ eidx,
                             unsigned short* __restrict__ wbT) {
    __shared__ float tile[64][65];
    const int be  = blockIdx.z;
    const int e   = eidx[be];
    const int k0  = blockIdx.y * 64;
    const int n0  = blockIdx.x * 64;
    const int bx  = n0 >> 7;
    const int cl0 = n0 & 127;
    const int kt0 = k0 >> 5;
    const float* src = W + (size_t)e * D_IN * D_HID;
    const int t = threadIdx.x;

#pragma unroll
    for (int p = 0; p < 4; ++p) {
        int row = p * 16 + (t >> 4);
        int col = (t & 15) * 4;
        const float* s = src + (size_t)(k0 + row) * D_HID + n0 + col;
        tile[row][col]     = s[0];
        tile[row][col + 1] = s[1];
        tile[row][col + 2] = s[2];
        tile[row][col + 3] = s[3];
    }
    __syncthreads();

    const int g   = (t >> 5) * 8;
    const int ktl = t >> 7;
    const int ks  = (t >> 5) & 3;
#pragma unroll
    for (int p = 0; p < 2; ++p) {
        int n = p * 32 + (t & 31);
        u16x8 v;
#pragma unroll
        for (int j = 0; j < 8; ++j) v[j] = f2bf(tile[g + j][n]);
        unsigned short* dst = wbT + ((size_t)(bx * 64 + kt0 + ktl)) * 8192 +
                              ((size_t)(ks * 256 + be * 128 + cl0 + n)) * 8;
        *(u16x8*)dst = v;
    }
}

// ------------------------------------------------------------------ GEMM --
// R14-R16 best state (byte-identical): one barrier per K-tile {12 ds_read |
// 4 gload_lds | vmcnt(4) | bar | 32 MFMA}, 4 buffers depth-3 slab staging,
// 16x16x32 MFMA, setprio, XCD swizzle (B L2-resident).
#define GLD16(gp, lp)                                                        \
    __builtin_amdgcn_global_load_lds(                                        \
        (const __attribute__((address_space(1))) void*)(gp),                 \
        (__attribute__((address_space(3))) void*)(lp), 16, 0, 0)

#define LDSV(SLOT) (*(const bf16x8*)&lds[(SLOT) * 8])

#define STAGE_A(SBAS, KT)                                                    \
    do {                                                                     \
        GLD16(gA0 + (size_t)(KT) * 8192,        &lds[((SBAS) + t512) * 8]);  \
        GLD16(gA0 + (size_t)(KT) * 8192 + 4096, &lds[((SBAS) + 512 + t512) * 8]); \
    } while (0)
#define STAGE_B(SBAS, KT)                                                    \
    do {                                                                     \
        GLD16(gB0 + (size_t)(KT) * 8192,        &lds[((SBAS) + 1024 + t512) * 8]); \
        GLD16(gB0 + (size_t)(KT) * 8192 + 4096, &lds[((SBAS) + 1536 + t512) * 8]); \
    } while (0)

#define MF(MI, AV)                                                                              \
    acc[MI][0] = __builtin_amdgcn_mfma_f32_16x16x32_bf16(AV, bf0, acc[MI][0], 0, 0, 0);         \
    acc[MI][1] = __builtin_amdgcn_mfma_f32_16x16x32_bf16(AV, bf1, acc[MI][1], 0, 0, 0);         \
    acc[MI][2] = __builtin_amdgcn_mfma_f32_16x16x32_bf16(AV, bf2, acc[MI][2], 0, 0, 0);         \
    acc[MI][3] = __builtin_amdgcn_mfma_f32_16x16x32_bf16(AV, bf3, acc[MI][3], 0, 0, 0);

#define TILE(RB, SB, KT, DO_STAGE, VMSTR)                                    \
    do {                                                                     \
        const int rbas  = (RB) * 2048;                                       \
        const int abase = rbas + aks + arow;                                 \
        const int bbase = rbas + 1024 + aks + brow;                          \
        bf16x8 bf0 = LDSV(bbase), bf1 = LDSV(bbase + 16),                    \
               bf2 = LDSV(bbase + 32), bf3 = LDSV(bbase + 48);               \
        bf16x8 a0 = LDSV(abase), a1 = LDSV(abase + 16),                      \
               a2 = LDSV(abase + 32), a3 = LDSV(abase + 48);                 \
        bf16x8 a4 = LDSV(abase + 64), a5 = LDSV(abase + 80),                 \
               a6 = LDSV(abase + 96), a7 = LDSV(abase + 112);                \
        if (DO_STAGE) { STAGE_A((SB) * 2048, KT); STAGE_B((SB) * 2048, KT); }\
        if (VMSTR[0]) asm volatile(VMSTR ::: "memory");                      \
        __builtin_amdgcn_s_barrier();                                        \
        __builtin_amdgcn_s_setprio(1);                                       \
        MF(0, a0) MF(1, a1) MF(2, a2) MF(3, a3)                              \
        MF(4, a4) MF(5, a5) MF(6, a6) MF(7, a7)                              \
        __builtin_amdgcn_s_setprio(0);                                       \
    } while (0)

__global__ __launch_bounds__(512, 2) void moe_gemm_kernel(
    const unsigned short* __restrict__ xb,   // slab order [mt64][kt64][1024]
    const unsigned short* __restrict__ wbT,  // slab order [bx16][kt64][1024]
    const float* __restrict__ b_exp,         // [8][D_HID]
    const int* __restrict__ eidx,
    const float* __restrict__ s12,           // [N_TOK][2]
    float* __restrict__ out) {
    __shared__ __align__(16) short lds[4 * 2048 * 8];  // 128 KiB

    const int t512 = threadIdx.x;
    const int lane = t512 & 63;
    const int w    = t512 >> 6;
    const int wm   = w >> 2;
    const int wn   = w & 3;

    const int bid = blockIdx.x;
    const int xcd = bid & 7;
    const int jb  = bid >> 3;
    const int bx  = xcd * 2 + (jb & 1);
    const int by  = jb >> 1;
    const int mbase = by * 256;
    const int nbase = bx * 128;

    const unsigned short* gA0 = xb  + ((size_t)by * 64) * 8192 + t512 * 8;
    const unsigned short* gB0 = wbT + ((size_t)bx * 64) * 8192 + t512 * 8;

    const int aks  = (lane >> 4) * 256;
    const int arow = wm * 128 + (lane & 15);
    const int brow = wn * 64 + (lane & 15);

    f32x4 acc[8][4];
#pragma unroll
    for (int mi = 0; mi < 8; ++mi)
#pragma unroll
        for (int ni = 0; ni < 4; ++ni) acc[mi][ni] = (f32x4){0.f, 0.f, 0.f, 0.f};

    STAGE_A(0, 0);    STAGE_B(0, 0);
    STAGE_A(2048, 1); STAGE_B(2048, 1);
    STAGE_A(4096, 2); STAGE_B(4096, 2);
    asm volatile("s_waitcnt vmcnt(4)" ::: "memory");
    __builtin_amdgcn_s_barrier();

#pragma unroll 4
    for (int t = 0; t < 61; ++t) {
        TILE(t & 3, (t + 3) & 3, t + 3, 1, "s_waitcnt vmcnt(4)");
    }
    TILE(1, 0, 0, 0, "s_waitcnt vmcnt(4)");   // tile 61 (no wait in practice)
    TILE(2, 0, 0, 0, "s_waitcnt vmcnt(0)");   // tile 62: retire tile 63
    TILE(3, 0, 0, 0, "");                     // tile 63

    // -------- epilogue: combine experts through LDS (f32) --------
    __syncthreads();
    float* fl = (float*)lds;
    if (wn >= 2) {
        float* reg = fl + (wm * 2 + (wn - 2)) * 8192;   // [128][64]
#pragma unroll
        for (int mi = 0; mi < 8; ++mi)
#pragma unroll
            for (int ni = 0; ni < 4; ++ni)
#pragma unroll
                for (int j = 0; j < 4; ++j) {
                    int row_l = mi * 16 + ((lane >> 4) << 2) + j;
                    int col_l = ni * 16 + (lane & 15);
                    reg[row_l * 64 + col_l] = acc[mi][ni][j];
                }
    }
    __syncthreads();
    if (wn < 2) {
        const float* reg = fl + (wm * 2 + wn) * 8192;
        const int e0 = eidx[0], e1 = eidx[1];
        const float* bb0 = b_exp + (size_t)e0 * D_HID;
        const float* bb1 = b_exp + (size_t)e1 * D_HID;
        const float2* s12v = (const float2*)s12;
        int   cc[4];
        float b0c[4], b1c[4];
#pragma unroll
        for (int ni = 0; ni < 4; ++ni) {
            cc[ni]  = nbase + wn * 64 + ni * 16 + (lane & 15);
            b0c[ni] = bb0[cc[ni]];
            b1c[ni] = bb1[cc[ni]];
        }
#pragma unroll
        for (int mi = 0; mi < 8; ++mi)
#pragma unroll
            for (int j = 0; j < 4; ++j) {
                int row_l = mi * 16 + ((lane >> 4) << 2) + j;
                int r = mbase + wm * 128 + row_l;
                float2 s = s12v[r];
#pragma unroll
                for (int ni = 0; ni < 4; ++ni) {
                    float y1 = reg[row_l * 64 + ni * 16 + (lane & 15)];
                    out[(size_t)r * D_HID + cc[ni]] =
                        s.x * (acc[mi][ni][j] + b0c[ni]) + s.y * (y1 + b1c[ni]);
                }
            }
    }
}

// ---------------------------------------------------------------- launch --
extern "C" void kernel_launch(void* const* d_in, const int* in_sizes, int n_in,
                              void* d_out, int out_size, void* d_ws, size_t ws_size,
                              hipStream_t stream) {
    const float* x         = (const float*)d_in[0];
    const float* W_experts = (const float*)d_in[1];
    const float* b_experts = (const float*)d_in[2];
    const float* W_gate    = (const float*)d_in[3];
    const float* b_gate    = (const float*)d_in[4];
    float* out = (float*)d_out;

    char* ws = (char*)d_ws;
    float* s12  = (float*)ws;                                        // 128 KiB
    int*   eidx = (int*)(ws + 131072);
    unsigned short* xb  = (unsigned short*)(ws + 262144);            // 64 MiB
    unsigned short* wbT = (unsigned short*)(ws + 262144 + 67108864); // 16 MiB
    float* part = out;   // 4.2 MB gate partials in d_out scratch (GEMM
                         // fully overwrites out afterwards, every call)

    xconv3_kernel<<<512, 256, 0, stream>>>(x, W_gate, xb, part);
    gatefin_kernel<<<256, 256, 0, stream>>>(part, b_gate, s12, eidx);
    wconv_kernel<<<dim3(32, 32, 2), 256, 0, stream>>>(W_experts, eidx, wbT);
    moe_gemm_kernel<<<1024, 512, 0, stream>>>(xb, wbT, b_experts, eidx, s12, out);
}